// Round 7
// baseline (36.261 us; speedup 1.0000x reference)
//
#include <hip/hip_runtime.h>

// InvariantPolynomial: out = sum_e xl[oi[e]] * xr[e] * f(|pos_e|)
// R7 = ABLATION ROUND: R6 graph kept byte-identical (build + edge kernel,
// 28.0us baseline), plus ONE extra probe kernel that grid-stride float4-reads
// the same 40MB (pos, xr, oi) with no gather, reducing into d_ws scratch.
// dur(probe) = Total_R7 - 28.0 - ~0.4 (node gap). This bisects the edge
// kernel's ~26us into {cold-stream cost} vs {xl-gather cost}.
//
// ws layout: [0,8KB) float LUT; [8KB, 8KB+2048*4) probe partials.

#define TN    2048
#define DMAXF 5.0f
#define TPB   256
#define EPT   8
#define TILE  (TPB * EPT)   // 2048 edges per block
#define PBLK  2048          // probe blocks

// 1/sqrt(E[silu(z)^2]); matched reference exactly (absmax 0.0, R1-R6)
__device__ __constant__ float kSiluCst = 1.6765581f;

__global__ __launch_bounds__(256) void build_lut_kernel(
    const float* __restrict__ W1, const float* __restrict__ W2,
    float* __restrict__ table, float* __restrict__ out)
{
    if (blockIdx.x == 0 && threadIdx.x == 0) out[0] = 0.0f;  // replay-safe reset

    int t = blockIdx.x * 256 + threadIdx.x;
    int entry = t >> 5;
    int k = t & 31;
    int kk = (k < 30) ? k : 29;

    float d  = (float)entry * (DMAXF / (float)TN);
    float t6 = 6.0f * d;                      // gaussian centers at t6 = 1..20
    const float w1scale = 1.0f / (1.12f * sqrtf(20.0f));

    float a = 0.0f;
    #pragma unroll
    for (int j = 0; j < 20; ++j) {
        float df = t6 - (float)(j + 1);
        float e  = __expf(-df * df);
        a = fmaf(e * w1scale, W1[j * 30 + kk], a);
    }
    float s = a / (1.0f + __expf(-a));        // silu

    float w2s = 0.0f;
    #pragma unroll
    for (int c = 0; c < 5; ++c) w2s += W2[kk * 5 + c];

    float contrib = (k < 30) ? s * w2s * (kSiluCst / sqrtf(30.0f)) : 0.0f;

    #pragma unroll
    for (int m = 16; m > 0; m >>= 1) contrib += __shfl_xor(contrib, m, 32);

    if (k == 0 && entry < TN) table[entry] = contrib;
}

__global__ __launch_bounds__(TPB) void edge_sum_kernel(
    const float* __restrict__ pos, const float* __restrict__ xr,
    const float* __restrict__ xl, const int* __restrict__ oi,
    const float* __restrict__ table, float* __restrict__ out, int E)
{
    __shared__ float lut[TN];
    __shared__ double swv[TPB / 64];

    const int tid = threadIdx.x;

    {   // stage 8KB LUT
        const float4* t4 = (const float4*)table;
        float4* l4 = (float4*)lut;
        l4[tid]       = t4[tid];
        l4[tid + TPB] = t4[tid + TPB];
    }
    __syncthreads();

    const float scale = (float)TN / DMAXF;
    const float umax  = (float)(TN - 1) - 1e-3f;

    const long tile0 = (long)blockIdx.x * TILE;
    const int  rem   = (int)min((long)TILE, (long)E - tile0);
    const int  e0    = tid * EPT;
    double acc = 0.0;

    if (e0 + EPT <= rem) {
        const long g0 = tile0 + e0;
        const float4* p4 = (const float4*)(pos + g0 * 3);
        float4 P0 = p4[0], P1 = p4[1], P2 = p4[2], P3 = p4[3], P4 = p4[4], P5 = p4[5];
        const float4* x4 = (const float4*)(xr + g0);
        float4 X0 = x4[0], X1 = x4[1];
        const int4* o4 = (const int4*)(oi + g0);
        int4 O0 = o4[0], O1 = o4[1];

        float xlv[EPT];
        xlv[0] = xl[O0.x]; xlv[1] = xl[O0.y]; xlv[2] = xl[O0.z]; xlv[3] = xl[O0.w];
        xlv[4] = xl[O1.x]; xlv[5] = xl[O1.y]; xlv[6] = xl[O1.z]; xlv[7] = xl[O1.w];

        float px[EPT] = {P0.x, P0.w, P1.z, P2.y, P3.x, P3.w, P4.z, P5.y};
        float py[EPT] = {P0.y, P1.x, P1.w, P2.z, P3.y, P4.x, P4.w, P5.z};
        float pz[EPT] = {P0.z, P1.y, P2.x, P2.w, P3.z, P4.y, P5.x, P5.w};
        float xrv[EPT] = {X0.x, X0.y, X0.z, X0.w, X1.x, X1.y, X1.z, X1.w};

        float fsum = 0.0f;
        #pragma unroll
        for (int j = 0; j < EPT; ++j) {
            float d  = sqrtf(fmaf(px[j], px[j], fmaf(py[j], py[j], pz[j] * pz[j])));
            float u  = fminf(d * scale, umax);
            int   i0 = (int)u;
            float fr = u - (float)i0;
            float f  = fmaf(fr, lut[i0 + 1] - lut[i0], lut[i0]);
            fsum = fmaf(f * xrv[j], xlv[j], fsum);
        }
        acc = (double)fsum;
    } else if (e0 < rem) {
        float fsum = 0.0f;
        for (int j = 0; j < EPT && e0 + j < rem; ++j) {
            long  ge = tile0 + e0 + j;
            float x = pos[3 * ge], y = pos[3 * ge + 1], z = pos[3 * ge + 2];
            float d  = sqrtf(fmaf(x, x, fmaf(y, y, z * z)));
            float u  = fminf(d * scale, umax);
            int   i0 = (int)u;
            float fr = u - (float)i0;
            float f  = fmaf(fr, lut[i0 + 1] - lut[i0], lut[i0]);
            fsum = fmaf(f * xr[ge], xl[oi[ge]], fsum);
        }
        acc = (double)fsum;
    }

    #pragma unroll
    for (int off = 32; off > 0; off >>= 1) acc += __shfl_down(acc, off);
    int lane = tid & 63, wv = tid >> 6;
    if (lane == 0) swv[wv] = acc;
    __syncthreads();
    if (tid == 0) {
        double bsum = (swv[0] + swv[1]) + (swv[2] + swv[3]);
        atomicAdd(out, (float)bsum);
    }
}

// B-probe: pure cold-stream read of the same 40MB (no gather), result -> ws.
__global__ __launch_bounds__(TPB) void stream_probe_kernel(
    const float4* __restrict__ pos4, const float4* __restrict__ xr4,
    const float4* __restrict__ oi4, float* __restrict__ wsout,
    long n_pos4, long n_xr4, long n_oi4)
{
    float4 s = {0.f, 0.f, 0.f, 0.f};
    const long stride = (long)gridDim.x * TPB;
    long i0 = (long)blockIdx.x * TPB + threadIdx.x;
    for (long i = i0; i < n_pos4; i += stride) {
        float4 v = pos4[i];
        s.x += v.x; s.y += v.y; s.z += v.z; s.w += v.w;
    }
    for (long i = i0; i < n_xr4; i += stride) {
        float4 v = xr4[i];
        s.x += v.x; s.y += v.y; s.z += v.z; s.w += v.w;
    }
    for (long i = i0; i < n_oi4; i += stride) {
        float4 v = oi4[i];   // int bits read as float: BW probe only
        s.x += v.x; s.y += v.y; s.z += v.z; s.w += v.w;
    }
    float acc = (s.x + s.y) + (s.z + s.w);
    #pragma unroll
    for (int off = 32; off > 0; off >>= 1) acc += __shfl_down(acc, off);
    __shared__ float sw[TPB / 64];
    int lane = threadIdx.x & 63, wv = threadIdx.x >> 6;
    if (lane == 0) sw[wv] = acc;
    __syncthreads();
    if (threadIdx.x == 0)
        wsout[blockIdx.x] = (sw[0] + sw[1]) + (sw[2] + sw[3]);
}

extern "C" void kernel_launch(void* const* d_in, const int* in_sizes, int n_in,
                              void* d_out, int out_size, void* d_ws, size_t ws_size,
                              hipStream_t stream) {
    const float* pos = (const float*)d_in[0];   // [E,3]
    const float* xr  = (const float*)d_in[1];   // [E,1]
    const float* xl  = (const float*)d_in[2];   // [N,1]
    const float* W1  = (const float*)d_in[3];   // [20,30]
    const float* W2  = (const float*)d_in[4];   // [30,5]
    const int*   oi  = (const int*)d_in[5];     // [E]
    float* out = (float*)d_out;

    int E = in_sizes[1];
    int nblk = (E + TILE - 1) / TILE;           // 977 for E=2M

    float* table   = (float*)d_ws;
    float* probew  = (float*)((char*)d_ws + (size_t)TN * sizeof(float));

    hipLaunchKernelGGL(build_lut_kernel, dim3((TN * 32) / 256), dim3(256), 0, stream,
                       W1, W2, table, out);
    hipLaunchKernelGGL(edge_sum_kernel, dim3(nblk), dim3(TPB), 0, stream,
                       pos, xr, xl, oi, table, out, E);
    hipLaunchKernelGGL(stream_probe_kernel, dim3(PBLK), dim3(TPB), 0, stream,
                       (const float4*)pos, (const float4*)xr, (const float4*)oi,
                       probew, (long)E * 3 / 4, (long)E / 4, (long)E / 4);
}